// Round 6
// baseline (811.328 us; speedup 1.0000x reference)
//
#include <hip/hip_runtime.h>

// Problem constants: B=4, L=1024, D=512, N=16, OUT=512, NL=2
#define BQ 4
#define LQ 1024
#define DQ 512
#define NQ 16
#define MQ (BQ*LQ)      // 4096 rows (b,l flattened)
#define CHUNK 32
#define NCH (LQ/CHUNK)  // 32 chunks
#define KQ 512
#define NFUSE 576       // 512 dt + 16 B + 16 C + 32 pad
#define NBLK 256        // persistent blocks (1 per CU -> co-resident, no deadlock)
#define NTHR 512        // 8 waves per block

typedef __bf16  bf16x8  __attribute__((ext_vector_type(8)));
typedef float   floatx4 __attribute__((ext_vector_type(4)));

__device__ __forceinline__ float softplus_f(float x) {
    return (x > 20.0f) ? x : log1pf(__expf(x));
}
__device__ __forceinline__ unsigned short f2b(float f) {
    union { float f; unsigned u; } x; x.f = f;
    unsigned r = x.u + 0x7fffu + ((x.u >> 16) & 1u);
    return (unsigned short)(r >> 16);
}
__device__ __forceinline__ float b2f(unsigned short u) {
    union { unsigned u; float f; } x; x.u = (unsigned)u << 16;
    return x.f;
}
__device__ __forceinline__ void load_lds16(const void* g, void* l) {
    __builtin_amdgcn_global_load_lds(
        (const __attribute__((address_space(1))) unsigned int*)g,
        (__attribute__((address_space(3))) unsigned int*)l, 16, 0, 0);
}

// one shared buffer reused by all phases (max 16.6 KB)
union SMem {
    float tile[64][65];                                    // transpose
    struct { unsigned short A[128*32]; unsigned short B[64*32]; } g;  // GEMM
};

// -------------------------------------------------------------------------
// device-wide barrier: counters zeroed by hipMemsetAsync before each launch.
// Each barrier index used exactly once per launch (no sense reversal needed).
// agent-scope release (fence+atomic) / acquire (spin load) handles cross-XCD
// L2 visibility; __syncthreads broadcasts within the block (same CU/L1).
// -------------------------------------------------------------------------
__device__ __forceinline__ void grid_sync(unsigned* ctr, int idx) {
    __syncthreads();
    if (threadIdx.x == 0) {
        __threadfence();
        __hip_atomic_fetch_add(&ctr[idx], 1u, __ATOMIC_ACQ_REL,
                               __HIP_MEMORY_SCOPE_AGENT);
        while (__hip_atomic_load(&ctr[idx], __ATOMIC_ACQUIRE,
                                 __HIP_MEMORY_SCOPE_AGENT) < NBLK)
            __builtin_amdgcn_s_sleep(8);
        __threadfence();
    }
    __syncthreads();
}

// -------------------------------------------------------------------------
// GEMM core: 128x64 tile, BK=32, 8 waves (4x2 of 32x32 wave tiles).
// A[M][512] bf16 row-major, Wt[N][512] bf16 (transposed weights).
// -------------------------------------------------------------------------
__device__ __forceinline__ void gemm_core(
    const unsigned short* __restrict__ Abf,
    const unsigned short* __restrict__ Wt,
    int bm, int bn, SMem* sm, floatx4 acc[2][2])
{
    const int tid = threadIdx.x;
    const int wave = tid >> 6, lane = tid & 63;
    const int mw = (wave & 3) * 32, nw = (wave >> 2) * 32;
    const int srow = lane >> 2, sg = (lane & 3) * 8;
    #pragma unroll
    for (int i = 0; i < 2; ++i)
        #pragma unroll
        for (int j = 0; j < 2; ++j) acc[i][j] = (floatx4){0.f,0.f,0.f,0.f};

    for (int k0 = 0; k0 < KQ; k0 += 32) {
        __syncthreads();   // prior frag reads (or prior phase's smem use) done
        load_lds16(Abf + (size_t)(bm + wave*16 + srow) * KQ + k0 + sg,
                   sm->g.A + wave * 16 * 32);
        if (wave < 4)
            load_lds16(Wt + (size_t)(bn + wave*16 + srow) * KQ + k0 + sg,
                       sm->g.B + wave * 16 * 32);
        __syncthreads();   // staging drained
        bf16x8 af0 = *(const bf16x8*)&sm->g.A[(mw      + (lane & 15)) * 32 + (lane >> 4) * 8];
        bf16x8 af1 = *(const bf16x8*)&sm->g.A[(mw + 16 + (lane & 15)) * 32 + (lane >> 4) * 8];
        bf16x8 bf0 = *(const bf16x8*)&sm->g.B[(nw      + (lane & 15)) * 32 + (lane >> 4) * 8];
        bf16x8 bf1 = *(const bf16x8*)&sm->g.B[(nw + 16 + (lane & 15)) * 32 + (lane >> 4) * 8];
        acc[0][0] = __builtin_amdgcn_mfma_f32_16x16x32_bf16(af0, bf0, acc[0][0], 0,0,0);
        acc[1][0] = __builtin_amdgcn_mfma_f32_16x16x32_bf16(af1, bf0, acc[1][0], 0,0,0);
        acc[0][1] = __builtin_amdgcn_mfma_f32_16x16x32_bf16(af0, bf1, acc[0][1], 0,0,0);
        acc[1][1] = __builtin_amdgcn_mfma_f32_16x16x32_bf16(af1, bf1, acc[1][1], 0,0,0);
    }
}

// plain epilogue: F32 -> Cf (fp32), else Cb (bf16)
template<bool F32>
__device__ __forceinline__ void gemm_plain_tile(
    const unsigned short* __restrict__ Abf,
    const unsigned short* __restrict__ Wt,
    int bm, int bn, const float* __restrict__ bias,
    float* __restrict__ Cf, unsigned short* __restrict__ Cb, int N, SMem* sm)
{
    floatx4 acc[2][2];
    gemm_core(Abf, Wt, bm, bn, sm, acc);
    const int lane = threadIdx.x & 63, wave = threadIdx.x >> 6;
    const int mw = (wave & 3) * 32, nw = (wave >> 2) * 32;
    const int col0 = lane & 15, rq = lane >> 4;
    #pragma unroll
    for (int nt = 0; nt < 2; ++nt) {
        int n = bn + nw + nt * 16 + col0;
        float bv = bias[n];
        #pragma unroll
        for (int mt = 0; mt < 2; ++mt)
            #pragma unroll
            for (int r = 0; r < 4; ++r) {
                int m = bm + mw + mt * 16 + rq * 4 + r;
                float v = acc[mt][nt][r] + bv;
                if (F32) Cf[(size_t)m * N + n] = v;
                else     Cb[(size_t)m * N + n] = f2b(v);
            }
    }
}

// fused epilogue: cols 0-511 dt(softplus->bf16), 512-527 Bm, 528-543 Cm
__device__ __forceinline__ void gemm_fused_tile(
    const unsigned short* __restrict__ Abf,
    const unsigned short* __restrict__ Wt,
    int bm, int bn,
    const float* __restrict__ bdt, const float* __restrict__ bB,
    const float* __restrict__ bC,
    unsigned short* __restrict__ dtb, float* __restrict__ Bm,
    float* __restrict__ Cm, SMem* sm)
{
    floatx4 acc[2][2];
    gemm_core(Abf, Wt, bm, bn, sm, acc);
    const int lane = threadIdx.x & 63, wave = threadIdx.x >> 6;
    const int mw = (wave & 3) * 32, nw = (wave >> 2) * 32;
    const int col0 = lane & 15, rq = lane >> 4;
    #pragma unroll
    for (int nt = 0; nt < 2; ++nt) {
        int nb = bn + nw + nt * 16;   // 16-col region selector (frag-uniform)
        int n  = nb + col0;
        if (nb < 512) {
            float bv = bdt[n];
            #pragma unroll
            for (int mt = 0; mt < 2; ++mt)
                #pragma unroll
                for (int r = 0; r < 4; ++r) {
                    int m = bm + mw + mt * 16 + rq * 4 + r;
                    dtb[(size_t)m * DQ + n] = f2b(softplus_f(acc[mt][nt][r] + bv));
                }
        } else if (nb < 528) {
            float bv = bB[n - 512];
            #pragma unroll
            for (int mt = 0; mt < 2; ++mt)
                #pragma unroll
                for (int r = 0; r < 4; ++r) {
                    int m = bm + mw + mt * 16 + rq * 4 + r;
                    Bm[(size_t)m * NQ + (n - 512)] = acc[mt][nt][r] + bv;
                }
        } else if (nb < 544) {
            float bv = bC[n - 528];
            #pragma unroll
            for (int mt = 0; mt < 2; ++mt)
                #pragma unroll
                for (int r = 0; r < 4; ++r) {
                    int m = bm + mw + mt * 16 + rq * 4 + r;
                    Cm[(size_t)m * NQ + (n - 528)] = acc[mt][nt][r] + bv;
                }
        }
        // nb >= 544: zero pad, skip
    }
}

// -------------------------------------------------------------------------
// 64x64 transpose+cast tile: dst[n][k] bf16 = src[k][n] fp32
// -------------------------------------------------------------------------
__device__ __forceinline__ void transpose64(
    const float* __restrict__ src, unsigned short* __restrict__ dst,
    int bk, int bn, SMem* sm)
{
    const int col = threadIdx.x & 63, r0 = threadIdx.x >> 6;  // 8 rows/pass
    __syncthreads();   // protect smem reuse across jobs
    #pragma unroll
    for (int i = 0; i < 64; i += 8)
        sm->tile[r0 + i][col] = src[(size_t)(bk + r0 + i) * KQ + bn + col];
    __syncthreads();
    #pragma unroll
    for (int i = 0; i < 64; i += 8)
        dst[(size_t)(bn + r0 + i) * KQ + bk + col] = f2b(sm->tile[col][r0 + i]);
}

// -------------------------------------------------------------------------
// scan phases (512 threads: d = tid)
// -------------------------------------------------------------------------
__device__ __forceinline__ void scan1_job(
    int b, int c,
    const unsigned short* __restrict__ dt, const unsigned short* __restrict__ y,
    const float* __restrict__ Bm, const float* __restrict__ A,
    float* __restrict__ ap, float* __restrict__ hf)
{
    const int d = threadIdx.x;
    float Ad[NQ];
    const float* Aptr = A + (size_t)d * NQ;
    #pragma unroll
    for (int n = 0; n < NQ; ++n) Ad[n] = Aptr[n];
    float h[NQ], prod[NQ];
    #pragma unroll
    for (int n = 0; n < NQ; ++n) { h[n] = 0.f; prod[n] = 1.f; }

    const int t0 = c * CHUNK;
    const unsigned short* dtp = dt + ((size_t)b*LQ + t0) * DQ + d;
    const unsigned short* yp  = y  + ((size_t)b*LQ + t0) * DQ + d;
    const float* bp = Bm + ((size_t)b*LQ + t0) * NQ;

    #pragma unroll 4
    for (int t = 0; t < CHUNK; ++t) {
        float dtv = b2f(dtp[(size_t)t * DQ]);
        float yv  = b2f(yp[(size_t)t * DQ]);
        float dty = dtv * yv;
        #pragma unroll
        for (int n = 0; n < NQ; ++n) {
            float a = __expf(dtv * Ad[n]);
            prod[n] *= a;
            h[n] = fmaf(a, h[n], dty * bp[t*NQ + n]);
        }
    }
    size_t base = ((size_t)(b*NCH + c) * DQ + d) * NQ;
    #pragma unroll
    for (int n = 0; n < NQ; n += 4) {
        *(float4*)(ap + base + n) = make_float4(prod[n], prod[n+1], prod[n+2], prod[n+3]);
        *(float4*)(hf + base + n) = make_float4(h[n], h[n+1], h[n+2], h[n+3]);
    }
}

__device__ __forceinline__ void scan2_thread(
    int g, float* ap, const float* __restrict__ hf)
{
    const int n = g & 15, d = (g >> 4) & 511, b = g >> 13;
    float h = 0.f;
    for (int c = 0; c < NCH; ++c) {
        size_t idx = ((size_t)(b*NCH + c) * DQ + d) * NQ + n;
        float a = ap[idx];
        float f = hf[idx];
        ap[idx] = h;
        h = fmaf(a, h, f);
    }
}

__device__ __forceinline__ void scan3_job(
    int b, int c,
    const unsigned short* __restrict__ dt, const unsigned short* __restrict__ y,
    const float* __restrict__ Bm, const float* __restrict__ Cm,
    const float* __restrict__ A, const float* __restrict__ Dsk,
    const float* __restrict__ hi, unsigned short* __restrict__ yact)
{
    const int d = threadIdx.x;
    float Ad[NQ];
    const float* Aptr = A + (size_t)d * NQ;
    #pragma unroll
    for (int n = 0; n < NQ; ++n) Ad[n] = Aptr[n];
    float h[NQ];
    size_t base = ((size_t)(b*NCH + c) * DQ + d) * NQ;
    #pragma unroll
    for (int n = 0; n < NQ; n += 4) {
        float4 v = *(const float4*)(hi + base + n);
        h[n] = v.x; h[n+1] = v.y; h[n+2] = v.z; h[n+3] = v.w;
    }
    float dskip = Dsk[d];

    const int t0 = c * CHUNK;
    const unsigned short* dtp = dt + ((size_t)b*LQ + t0) * DQ + d;
    const unsigned short* yp  = y  + ((size_t)b*LQ + t0) * DQ + d;
    const float* bp = Bm + ((size_t)b*LQ + t0) * NQ;
    const float* cp = Cm + ((size_t)b*LQ + t0) * NQ;
    unsigned short* op = yact + ((size_t)b*LQ + t0) * DQ + d;

    #pragma unroll 4
    for (int t = 0; t < CHUNK; ++t) {
        float dtv = b2f(dtp[(size_t)t * DQ]);
        float yv  = b2f(yp[(size_t)t * DQ]);
        float dty = dtv * yv;
        float acc = 0.f;
        #pragma unroll
        for (int n = 0; n < NQ; ++n) {
            float a = __expf(dtv * Ad[n]);
            h[n] = fmaf(a, h[n], dty * bp[t*NQ + n]);
            acc = fmaf(h[n], cp[t*NQ + n], acc);
        }
        float v = acc + dskip * yv;
        op[(size_t)t * DQ] = f2b(fmaxf(v, 0.f));
    }
}

// ===========================================================================
// THE persistent mega-kernel: whole network, 11 grid barriers.
// ===========================================================================
__global__ __launch_bounds__(NTHR) void s6_mega(
    const float* __restrict__ x, const float* __restrict__ A,
    const float* __restrict__ Dsk,
    const float* __restrict__ WB, const float* __restrict__ bB,
    const float* __restrict__ WC, const float* __restrict__ bC,
    const float* __restrict__ Wdt, const float* __restrict__ bdt,
    const float* __restrict__ Wlin, const float* __restrict__ blin,
    const float* __restrict__ Wdec, const float* __restrict__ bdec,
    float* __restrict__ out,
    float* __restrict__ Bm, float* __restrict__ Cm,
    float* __restrict__ ap, float* __restrict__ hf,
    unsigned short* __restrict__ y16, unsigned short* __restrict__ dtb16,
    unsigned short* __restrict__ yact16,
    unsigned short* __restrict__ Wf, unsigned short* __restrict__ Wt_lin,
    unsigned short* __restrict__ Wt_dec,
    unsigned* ctr)
{
    __shared__ SMem sm;
    const int blk = blockIdx.x, tid = threadIdx.x;

    // ---------------- prep: cast x, transpose weights, pack B/C ------------
    for (int i = blk * NTHR + tid; i < MQ * DQ / 4; i += NBLK * NTHR) {
        float4 v = *(const float4*)(x + (size_t)i * 4);
        ushort4 o;
        o.x = f2b(v.x); o.y = f2b(v.y); o.z = f2b(v.z); o.w = f2b(v.w);
        *(ushort4*)(y16 + (size_t)i * 4) = o;
    }
    for (int job = blk; job < 5 * 64; job += NBLK) {
        int mat = job >> 6, t = job & 63;
        const float* src; unsigned short* dst;
        switch (mat) {
            case 0:  src = Wdt;                  dst = Wf;                    break;
            case 1:  src = Wdt + (size_t)KQ*KQ;  dst = Wf + (size_t)NFUSE*KQ; break;
            case 2:  src = Wlin;                 dst = Wt_lin;                break;
            case 3:  src = Wlin + (size_t)KQ*KQ; dst = Wt_lin + (size_t)KQ*KQ;break;
            default: src = Wdec;                 dst = Wt_dec;                break;
        }
        transpose64(src, dst, (t & 7) * 64, (t >> 3) * 64, &sm);
    }
    for (int job = blk; job < 128; job += NBLK) {
        int layer = job >> 6, r = job & 63;
        unsigned short* dst = Wf + (size_t)layer * NFUSE * KQ + (size_t)(512 + r) * KQ;
        int k = tid;
        unsigned short v = 0;
        if (r < 16)
            v = f2b(WB[(size_t)layer * DQ * NQ + (size_t)k * NQ + r]);
        else if (r < 32)
            v = f2b(WC[(size_t)layer * DQ * NQ + (size_t)k * NQ + (r - 16)]);
        dst[k] = v;
    }
    grid_sync(ctr, 0);

    // ---------------- layers ----------------------------------------------
    for (int layer = 0; layer < 2; ++layer) {
        const unsigned short* Wfl = Wf + (size_t)layer * NFUSE * KQ;
        const float* bdt_l = bdt + (size_t)layer * DQ;
        const float* bB_l  = bB  + (size_t)layer * NQ;
        const float* bC_l  = bC  + (size_t)layer * NQ;
        const float* A_l   = A   + (size_t)layer * DQ * NQ;
        const float* Dsk_l = Dsk + (size_t)layer * DQ;

        // fused dt/B/C GEMM: 32 m-tiles x 9 n-tiles = 288 jobs
        for (int job = blk; job < 32 * 9; job += NBLK)
            gemm_fused_tile(y16, Wfl, (job / 9) * 128, (job % 9) * 64,
                            bdt_l, bB_l, bC_l, dtb16, Bm, Cm, &sm);
        grid_sync(ctr, 1 + layer * 5);

        for (int job = blk; job < BQ * NCH; job += NBLK)
            scan1_job(job >> 5, job & 31, dtb16, y16, Bm, A_l, ap, hf);
        grid_sync(ctr, 2 + layer * 5);

        { int g = blk * NTHR + tid; if (g < BQ * DQ * NQ) scan2_thread(g, ap, hf); }
        grid_sync(ctr, 3 + layer * 5);

        for (int job = blk; job < BQ * NCH; job += NBLK)
            scan3_job(job >> 5, job & 31, dtb16, y16, Bm, Cm, A_l, Dsk_l,
                      ap, yact16);
        grid_sync(ctr, 4 + layer * 5);

        // y = yact @ Wlin + blin (bf16 out, overwrites y16): 32x8 = 256 jobs
        for (int job = blk; job < 32 * 8; job += NBLK)
            gemm_plain_tile<false>(yact16, Wt_lin + (size_t)layer*KQ*KQ,
                                   (job >> 3) * 128, (job & 7) * 64,
                                   blin + (size_t)layer * DQ,
                                   nullptr, y16, DQ, &sm);
        grid_sync(ctr, 5 + layer * 5);
    }

    // decoder: fp32 out
    for (int job = blk; job < 32 * 8; job += NBLK)
        gemm_plain_tile<true>(y16, Wt_dec, (job >> 3) * 128, (job & 7) * 64,
                              bdec, out, nullptr, DQ, &sm);
}

// ---------------------------------------------------------------------------
extern "C" void kernel_launch(void* const* d_in, const int* in_sizes, int n_in,
                              void* d_out, int out_size, void* d_ws, size_t ws_size,
                              hipStream_t stream)
{
    const float* x    = (const float*)d_in[0];
    const float* A    = (const float*)d_in[1];
    const float* Dsk  = (const float*)d_in[2];
    const float* WB   = (const float*)d_in[3];
    const float* bB   = (const float*)d_in[4];
    const float* WC   = (const float*)d_in[5];
    const float* bC   = (const float*)d_in[6];
    const float* Wdt  = (const float*)d_in[7];
    const float* bdt  = (const float*)d_in[8];
    const float* Wlin = (const float*)d_in[9];
    const float* blin = (const float*)d_in[10];
    const float* Wdec = (const float*)d_in[11];
    const float* bdec = (const float*)d_in[12];
    float* out = (float*)d_out;

    // workspace layout
    char* cur = (char*)d_ws;
    float* Bm   = (float*)cur;           cur += (size_t)MQ*NQ*4;          // 256 KB
    float* Cm   = (float*)cur;           cur += (size_t)MQ*NQ*4;          // 256 KB
    float* ap   = (float*)cur;           cur += (size_t)BQ*NCH*DQ*NQ*4;   // 4 MB
    float* hf   = (float*)cur;           cur += (size_t)BQ*NCH*DQ*NQ*4;   // 4 MB
    unsigned short* y16    = (unsigned short*)cur; cur += (size_t)MQ*DQ*2;   // 4 MB
    unsigned short* dtb16  = (unsigned short*)cur; cur += (size_t)MQ*DQ*2;   // 4 MB
    unsigned short* yact16 = (unsigned short*)cur; cur += (size_t)MQ*DQ*2;   // 4 MB
    unsigned short* Wf     = (unsigned short*)cur; cur += (size_t)2*NFUSE*KQ*2; // 1.125 MB
    unsigned short* Wt_lin = (unsigned short*)cur; cur += (size_t)2*KQ*KQ*2;   // 1 MB
    unsigned short* Wt_dec = (unsigned short*)cur; cur += (size_t)KQ*KQ*2;     // 0.5 MB
    unsigned* ctr = (unsigned*)cur;      cur += 64;                      // barrier counters

    // zero the barrier counters (ws is re-poisoned to 0xAA before every launch)
    hipMemsetAsync(ctr, 0, 64, stream);

    s6_mega<<<dim3(NBLK), dim3(NTHR), 0, stream>>>(
        x, A, Dsk, WB, bB, WC, bC, Wdt, bdt, Wlin, blin, Wdec, bdec, out,
        Bm, Cm, ap, hf, y16, dtb16, yact16, Wf, Wt_lin, Wt_dec, ctr);
}

// Round 7
// 226.806 us; speedup vs baseline: 3.5772x; 3.5772x over previous
//
#include <hip/hip_runtime.h>

// Problem constants: B=4, L=1024, D=512, N=16, OUT=512, NL=2
#define BQ 4
#define LQ 1024
#define DQ 512
#define NQ 16
#define MQ (BQ*LQ)      // 4096 rows (b,l flattened)
#define CHUNK 32
#define NCH (LQ/CHUNK)  // 32 chunks
#define KQ 512
#define NFUSE 576       // 512 dt + 16 B + 16 C + 32 pad

typedef __bf16  bf16x8  __attribute__((ext_vector_type(8)));
typedef float   floatx4 __attribute__((ext_vector_type(4)));

__device__ __forceinline__ float softplus_f(float x) {
    return (x > 20.0f) ? x : log1pf(__expf(x));
}
__device__ __forceinline__ unsigned short f2b(float f) {
    union { float f; unsigned u; } x; x.f = f;
    unsigned r = x.u + 0x7fffu + ((x.u >> 16) & 1u);
    return (unsigned short)(r >> 16);
}
__device__ __forceinline__ float b2f(unsigned short u) {
    union { unsigned u; float f; } x; x.u = (unsigned)u << 16;
    return x.f;
}
__device__ __forceinline__ void load_lds16(const void* g, void* l) {
    __builtin_amdgcn_global_load_lds(
        (const __attribute__((address_space(1))) unsigned int*)g,
        (__attribute__((address_space(3))) unsigned int*)l, 16, 0, 0);
}

// ===========================================================================
// Double-buffered MFMA GEMM: 64x64 tile, BK=64, 4 waves (wave tile 32x32).
// LDS layout: row pitch 64 elems (128B) with XOR-16B swizzle -> staging stays
// contiguous for global_load_lds AND ds_read_b128 is 2-way (free) instead of
// the 8-way conflict of the r2-r6 layout. One __syncthreads per k-iter;
// prefetch of tile k+1 issued right after the barrier so the next barrier's
// vmcnt(0) drain overlaps this iter's compute (prefetch distance 1).
// ===========================================================================
// stage one 64-row x 64-elem bf16 tile (8 KB): wave stages 16 rows (2 issues
// of 1 KB). Source granule is XOR-permuted so LDS slot s of row r holds
// global k-granule s^(r&7).
__device__ __forceinline__ void stage_tile(
    const unsigned short* g, unsigned short* lds, int wave, int lane)
{
    const int rsub = lane >> 3;              // row within 8-row issue
    const int gsrc = (lane & 7) ^ rsub;      // swizzled source granule
    #pragma unroll
    for (int j = 0; j < 2; ++j) {
        int rbase = wave * 16 + j * 8;
        load_lds16(g + (size_t)(rbase + rsub) * KQ + gsrc * 8,
                   lds + (size_t)rbase * 64);
    }
}

__device__ __forceinline__ void gemm_db_core(
    const unsigned short* __restrict__ Abf,
    const unsigned short* __restrict__ Wt,
    int bm, int bn,
    unsigned short (*As)[64*64], unsigned short (*Bs)[64*64],
    floatx4 acc[2][2])
{
    const int lane = threadIdx.x & 63, wave = threadIdx.x >> 6;
    const int mw = (wave & 1) * 32, nw = (wave >> 1) * 32;
    const int r15 = lane & 15, q = lane >> 4;
    const int slot0 = q ^ (r15 & 7);         // ks=0 slot; ks=1 slot = slot0^4

    #pragma unroll
    for (int i = 0; i < 2; ++i)
        #pragma unroll
        for (int j = 0; j < 2; ++j) acc[i][j] = (floatx4){0.f,0.f,0.f,0.f};

    const unsigned short* ga = Abf + (size_t)bm * KQ;
    const unsigned short* gb = Wt  + (size_t)bn * KQ;
    stage_tile(ga, As[0], wave, lane);
    stage_tile(gb, Bs[0], wave, lane);

    #pragma unroll
    for (int it = 0; it < 8; ++it) {
        __syncthreads();    // drains loads issued LAST iter (1 iter in flight)
        if (it < 7) {
            stage_tile(ga + (it + 1) * 64, As[(it + 1) & 1], wave, lane);
            stage_tile(gb + (it + 1) * 64, Bs[(it + 1) & 1], wave, lane);
        }
        const unsigned short* a = As[it & 1];
        const unsigned short* b = Bs[it & 1];
        #pragma unroll
        for (int ks = 0; ks < 2; ++ks) {
            int slot = slot0 ^ (ks * 4);
            bf16x8 af0 = *(const bf16x8*)&a[(mw      + r15) * 64 + slot * 8];
            bf16x8 af1 = *(const bf16x8*)&a[(mw + 16 + r15) * 64 + slot * 8];
            bf16x8 bf0 = *(const bf16x8*)&b[(nw      + r15) * 64 + slot * 8];
            bf16x8 bf1 = *(const bf16x8*)&b[(nw + 16 + r15) * 64 + slot * 8];
            acc[0][0] = __builtin_amdgcn_mfma_f32_16x16x32_bf16(af0, bf0, acc[0][0], 0,0,0);
            acc[1][0] = __builtin_amdgcn_mfma_f32_16x16x32_bf16(af1, bf0, acc[1][0], 0,0,0);
            acc[0][1] = __builtin_amdgcn_mfma_f32_16x16x32_bf16(af0, bf1, acc[0][1], 0,0,0);
            acc[1][1] = __builtin_amdgcn_mfma_f32_16x16x32_bf16(af1, bf1, acc[1][1], 0,0,0);
        }
    }
}

// ---------------------------------------------------------------------------
// Plain GEMM: out = A@Wt^T + bias. F32OUT: fp32 Cf, else bf16 Cb.
// ---------------------------------------------------------------------------
template<bool F32OUT>
__global__ __launch_bounds__(256) void gemm_db(
    const unsigned short* __restrict__ Abf,
    const unsigned short* __restrict__ Wt,
    const float* __restrict__ bias,
    float* __restrict__ Cf, unsigned short* __restrict__ Cb, int N)
{
    __shared__ __align__(16) unsigned short As[2][64*64];  // 16 KB
    __shared__ __align__(16) unsigned short Bs[2][64*64];  // 16 KB
    const int bm = blockIdx.x * 64, bn = blockIdx.y * 64;
    floatx4 acc[2][2];
    gemm_db_core(Abf, Wt, bm, bn, As, Bs, acc);

    const int lane = threadIdx.x & 63, wave = threadIdx.x >> 6;
    const int mw = (wave & 1) * 32, nw = (wave >> 1) * 32;
    const int col0 = lane & 15, rq = lane >> 4;
    #pragma unroll
    for (int nt = 0; nt < 2; ++nt) {
        int n = bn + nw + nt * 16 + col0;
        float bv = bias[n];
        #pragma unroll
        for (int mt = 0; mt < 2; ++mt)
            #pragma unroll
            for (int r = 0; r < 4; ++r) {
                int m = bm + mw + mt * 16 + rq * 4 + r;
                float v = acc[mt][nt][r] + bv;
                if (F32OUT) Cf[(size_t)m * N + n] = v;
                else        Cb[(size_t)m * N + n] = f2b(v);
            }
    }
}

// ---------------------------------------------------------------------------
// Fused dt/B/C GEMM: Wt rows 0-511 Wdt^T, 512-527 WB^T, 528-543 WC^T,
// 544-575 zero. dt written bf16 (softplus fused).
// ---------------------------------------------------------------------------
__global__ __launch_bounds__(256) void gemm_db_fused(
    const unsigned short* __restrict__ Abf,
    const unsigned short* __restrict__ Wt,
    const float* __restrict__ bdt, const float* __restrict__ bB,
    const float* __restrict__ bC,
    unsigned short* __restrict__ dtb, float* __restrict__ Bm, float* __restrict__ Cm)
{
    __shared__ __align__(16) unsigned short As[2][64*64];
    __shared__ __align__(16) unsigned short Bs[2][64*64];
    const int bm = blockIdx.x * 64, bn = blockIdx.y * 64;
    floatx4 acc[2][2];
    gemm_db_core(Abf, Wt, bm, bn, As, Bs, acc);

    const int lane = threadIdx.x & 63, wave = threadIdx.x >> 6;
    const int mw = (wave & 1) * 32, nw = (wave >> 1) * 32;
    const int col0 = lane & 15, rq = lane >> 4;
    #pragma unroll
    for (int nt = 0; nt < 2; ++nt) {
        int nb = bn + nw + nt * 16;     // 16-col region selector (frag-uniform)
        int n  = nb + col0;
        if (nb < 512) {
            float bv = bdt[n];
            #pragma unroll
            for (int mt = 0; mt < 2; ++mt)
                #pragma unroll
                for (int r = 0; r < 4; ++r) {
                    int m = bm + mw + mt * 16 + rq * 4 + r;
                    dtb[(size_t)m * DQ + n] = f2b(softplus_f(acc[mt][nt][r] + bv));
                }
        } else if (nb < 528) {
            float bv = bB[n - 512];
            #pragma unroll
            for (int mt = 0; mt < 2; ++mt)
                #pragma unroll
                for (int r = 0; r < 4; ++r) {
                    int m = bm + mw + mt * 16 + rq * 4 + r;
                    Bm[(size_t)m * NQ + (n - 512)] = acc[mt][nt][r] + bv;
                }
        } else if (nb < 544) {
            float bv = bC[n - 528];
            #pragma unroll
            for (int mt = 0; mt < 2; ++mt)
                #pragma unroll
                for (int r = 0; r < 4; ++r) {
                    int m = bm + mw + mt * 16 + rq * 4 + r;
                    Cm[(size_t)m * NQ + (n - 528)] = acc[mt][nt][r] + bv;
                }
        }
        // nb >= 544: zero pad, skip
    }
}

// ---------------------------------------------------------------------------
// fp32 -> bf16 cast (4 elems/thread)
// ---------------------------------------------------------------------------
__global__ __launch_bounds__(256) void cast_bf16_kernel(
    const float* __restrict__ in, unsigned short* __restrict__ out)
{
    size_t i = ((size_t)blockIdx.x * 256 + threadIdx.x) * 4;
    float4 v = *(const float4*)(in + i);
    ushort4 o;
    o.x = f2b(v.x); o.y = f2b(v.y); o.z = f2b(v.z); o.w = f2b(v.w);
    *(ushort4*)(out + i) = o;
}

// ---------------------------------------------------------------------------
// All weight transposes in one launch. block (32,8), grid (16,16,5).
// ---------------------------------------------------------------------------
__global__ __launch_bounds__(256) void transpose_all(
    const float* __restrict__ Wdt, const float* __restrict__ Wlin,
    const float* __restrict__ Wdec,
    unsigned short* __restrict__ Wf, unsigned short* __restrict__ Wt_lin,
    unsigned short* __restrict__ Wt_dec)
{
    const float* src; unsigned short* dst;
    switch (blockIdx.z) {
        case 0:  src = Wdt;                  dst = Wf;                    break;
        case 1:  src = Wdt + (size_t)KQ*KQ;  dst = Wf + (size_t)NFUSE*KQ; break;
        case 2:  src = Wlin;                 dst = Wt_lin;                break;
        case 3:  src = Wlin + (size_t)KQ*KQ; dst = Wt_lin + (size_t)KQ*KQ;break;
        default: src = Wdec;                 dst = Wt_dec;                break;
    }
    __shared__ float tile[32][33];
    int bx = blockIdx.x * 32, by = blockIdx.y * 32;
    int tx = threadIdx.x, ty = threadIdx.y;
    #pragma unroll
    for (int i = 0; i < 32; i += 8)
        tile[ty + i][tx] = src[(size_t)(bx + ty + i) * KQ + by + tx];
    __syncthreads();
    #pragma unroll
    for (int i = 0; i < 32; i += 8)
        dst[(size_t)(by + ty + i) * KQ + bx + tx] = f2b(tile[tx][ty + i]);
}

// ---------------------------------------------------------------------------
// pack WB/WC transposed (bf16) into rows 512..575 of fused weights.
// ---------------------------------------------------------------------------
__global__ __launch_bounds__(256) void pack_bc_kernel(
    const float* __restrict__ WB, const float* __restrict__ WC,
    unsigned short* __restrict__ Wf)
{
    int r = blockIdx.x;            // 0..63
    int layer = blockIdx.y;
    unsigned short* dst = Wf + (size_t)layer * NFUSE * KQ + (size_t)(512 + r) * KQ;
    const float* src = nullptr;
    int n = 0;
    if (r < 16)      { src = WB + (size_t)layer * DQ * NQ; n = r; }
    else if (r < 32) { src = WC + (size_t)layer * DQ * NQ; n = r - 16; }
    for (int k = threadIdx.x; k < KQ; k += 256)
        dst[k] = src ? f2b(src[(size_t)k * NQ + n]) : (unsigned short)0;
}

// ---------------------------------------------------------------------------
// Scan phase 1: per (b,d,chunk) cumulative a-product + local h (zero-init).
// ---------------------------------------------------------------------------
__global__ __launch_bounds__(256) void scan_phase1(
    const unsigned short* __restrict__ dt, const unsigned short* __restrict__ y,
    const float* __restrict__ Bm, const float* __restrict__ A,
    float* __restrict__ ap, float* __restrict__ hf)
{
    int idx  = blockIdx.x;
    int dblk = idx & 1;
    int c    = (idx >> 1) & (NCH - 1);
    int b    = idx >> 6;
    int d    = dblk * 256 + threadIdx.x;

    float Ad[NQ];
    const float* Aptr = A + (size_t)d * NQ;
    #pragma unroll
    for (int n = 0; n < NQ; ++n) Ad[n] = Aptr[n];

    float h[NQ], prod[NQ];
    #pragma unroll
    for (int n = 0; n < NQ; ++n) { h[n] = 0.f; prod[n] = 1.f; }

    int t0 = c * CHUNK;
    const unsigned short* dtp = dt + ((size_t)b*LQ + t0) * DQ + d;
    const unsigned short* yp  = y  + ((size_t)b*LQ + t0) * DQ + d;
    const float* bp  = Bm + ((size_t)b*LQ + t0) * NQ;

    #pragma unroll 4
    for (int t = 0; t < CHUNK; ++t) {
        float dtv = b2f(dtp[(size_t)t * DQ]);
        float yv  = b2f(yp[(size_t)t * DQ]);
        float dty = dtv * yv;
        #pragma unroll
        for (int n = 0; n < NQ; ++n) {
            float a = __expf(dtv * Ad[n]);
            prod[n] *= a;
            h[n] = fmaf(a, h[n], dty * bp[t*NQ + n]);
        }
    }
    size_t base = ((size_t)(b*NCH + c) * DQ + d) * NQ;
    #pragma unroll
    for (int n = 0; n < NQ; n += 4) {
        *(float4*)(ap + base + n) = make_float4(prod[n], prod[n+1], prod[n+2], prod[n+3]);
        *(float4*)(hf + base + n) = make_float4(h[n], h[n+1], h[n+2], h[n+3]);
    }
}

// ---------------------------------------------------------------------------
// Scan phase 2: scan over NCH chunk summaries; h_init in-place over ap.
// Loads batched in groups of 8 (independent) -> 4 latency rounds, not 32.
// ---------------------------------------------------------------------------
__global__ __launch_bounds__(256) void scan_phase2(
    float* ap, const float* __restrict__ hf)
{
    int g = blockIdx.x * 256 + threadIdx.x;   // B*D*N threads
    int n = g & (NQ - 1);
    int d = (g >> 4) & (DQ - 1);
    int b = g >> 13;
    const size_t stride = (size_t)DQ * NQ;
    size_t base = ((size_t)b * NCH * DQ + d) * NQ + n;
    float h = 0.f;
    for (int c0 = 0; c0 < NCH; c0 += 8) {
        float a[8], f[8];
        #pragma unroll
        for (int j = 0; j < 8; ++j) {
            size_t idx = base + (size_t)(c0 + j) * stride;
            a[j] = ap[idx];
            f[j] = hf[idx];
        }
        #pragma unroll
        for (int j = 0; j < 8; ++j) {
            size_t idx = base + (size_t)(c0 + j) * stride;
            ap[idx] = h;
            h = fmaf(a[j], h, f[j]);
        }
    }
}

// ---------------------------------------------------------------------------
// Scan phase 3: recompute local scan with h_init, emit bf16
// yact = relu(sum_n h*Cm + Dskip*y)
// ---------------------------------------------------------------------------
__global__ __launch_bounds__(256) void scan_phase3(
    const unsigned short* __restrict__ dt, const unsigned short* __restrict__ y,
    const float* __restrict__ Bm, const float* __restrict__ Cm,
    const float* __restrict__ A, const float* __restrict__ Dsk,
    const float* __restrict__ hi, unsigned short* __restrict__ yact)
{
    int idx  = blockIdx.x;
    int dblk = idx & 1;
    int c    = (idx >> 1) & (NCH - 1);
    int b    = idx >> 6;
    int d    = dblk * 256 + threadIdx.x;

    float Ad[NQ];
    const float* Aptr = A + (size_t)d * NQ;
    #pragma unroll
    for (int n = 0; n < NQ; ++n) Ad[n] = Aptr[n];

    float h[NQ];
    size_t base = ((size_t)(b*NCH + c) * DQ + d) * NQ;
    #pragma unroll
    for (int n = 0; n < NQ; n += 4) {
        float4 v = *(const float4*)(hi + base + n);
        h[n] = v.x; h[n+1] = v.y; h[n+2] = v.z; h[n+3] = v.w;
    }
    float dskip = Dsk[d];

    int t0 = c * CHUNK;
    const unsigned short* dtp = dt + ((size_t)b*LQ + t0) * DQ + d;
    const unsigned short* yp  = y  + ((size_t)b*LQ + t0) * DQ + d;
    const float* bp  = Bm + ((size_t)b*LQ + t0) * NQ;
    const float* cp  = Cm + ((size_t)b*LQ + t0) * NQ;
    unsigned short* op = yact + ((size_t)b*LQ + t0) * DQ + d;

    #pragma unroll 4
    for (int t = 0; t < CHUNK; ++t) {
        float dtv = b2f(dtp[(size_t)t * DQ]);
        float yv  = b2f(yp[(size_t)t * DQ]);
        float dty = dtv * yv;
        float acc = 0.f;
        #pragma unroll
        for (int n = 0; n < NQ; ++n) {
            float a = __expf(dtv * Ad[n]);
            h[n] = fmaf(a, h[n], dty * bp[t*NQ + n]);
            acc = fmaf(h[n], cp[t*NQ + n], acc);
        }
        float v = acc + dskip * yv;
        op[(size_t)t * DQ] = f2b(fmaxf(v, 0.f));
    }
}

// ---------------------------------------------------------------------------
extern "C" void kernel_launch(void* const* d_in, const int* in_sizes, int n_in,
                              void* d_out, int out_size, void* d_ws, size_t ws_size,
                              hipStream_t stream)
{
    const float* x    = (const float*)d_in[0];
    const float* A    = (const float*)d_in[1];
    const float* Dsk  = (const float*)d_in[2];
    const float* WB   = (const float*)d_in[3];
    const float* bB   = (const float*)d_in[4];
    const float* WC   = (const float*)d_in[5];
    const float* bC   = (const float*)d_in[6];
    const float* Wdt  = (const float*)d_in[7];
    const float* bdt  = (const float*)d_in[8];
    const float* Wlin = (const float*)d_in[9];
    const float* blin = (const float*)d_in[10];
    const float* Wdec = (const float*)d_in[11];
    const float* bdec = (const float*)d_in[12];
    float* out = (float*)d_out;

    // workspace layout
    char* cur = (char*)d_ws;
    float* Bm   = (float*)cur;           cur += (size_t)MQ*NQ*4;          // 256 KB
    float* Cm   = (float*)cur;           cur += (size_t)MQ*NQ*4;          // 256 KB
    float* ap   = (float*)cur;           cur += (size_t)BQ*NCH*DQ*NQ*4;   // 4 MB
    float* hf   = (float*)cur;           cur += (size_t)BQ*NCH*DQ*NQ*4;   // 4 MB
    unsigned short* y16    = (unsigned short*)cur; cur += (size_t)MQ*DQ*2;   // 4 MB
    unsigned short* dtb16  = (unsigned short*)cur; cur += (size_t)MQ*DQ*2;   // 4 MB
    unsigned short* yact16 = (unsigned short*)cur; cur += (size_t)MQ*DQ*2;   // 4 MB
    unsigned short* Wf     = (unsigned short*)cur; cur += (size_t)2*NFUSE*KQ*2; // 1.125 MB
    unsigned short* Wt_lin = (unsigned short*)cur; cur += (size_t)2*KQ*KQ*2;   // 1 MB
    unsigned short* Wt_dec = (unsigned short*)cur; cur += (size_t)KQ*KQ*2;     // 0.5 MB

    dim3 blk(256);
    dim3 blkT(32, 8);

    // weight prep (every call; inputs restored before each timed launch)
    transpose_all<<<dim3(16,16,5), blkT, 0, stream>>>(
        Wdt, Wlin, Wdec, Wf, Wt_lin, Wt_dec);
    pack_bc_kernel<<<dim3(64, 2), blk, 0, stream>>>(WB, WC, Wf);
    cast_bf16_kernel<<<dim3(MQ*DQ/1024), blk, 0, stream>>>(x, y16);

    dim3 gFused(MQ/64, NFUSE/64);   // 64 x 9 = 576 blocks
    dim3 gOut(MQ/64, DQ/64);        // 64 x 8 = 512 blocks
    for (int layer = 0; layer < 2; ++layer) {
        // dt (softplus, ->bf16) + Bm + Cm in one double-buffered MFMA GEMM
        gemm_db_fused<<<gFused, blk, 0, stream>>>(
            y16, Wf + (size_t)layer*NFUSE*KQ,
            bdt + (size_t)layer*DQ, bB + (size_t)layer*NQ, bC + (size_t)layer*NQ,
            dtb16, Bm, Cm);
        // chunked scan (bf16 activations)
        scan_phase1<<<dim3(BQ*NCH*(DQ/256)), blk, 0, stream>>>(
            dtb16, y16, Bm, A + (size_t)layer*DQ*NQ, ap, hf);
        scan_phase2<<<dim3(BQ*DQ*NQ/256), blk, 0, stream>>>(ap, hf);
        scan_phase3<<<dim3(BQ*NCH*(DQ/256)), blk, 0, stream>>>(
            dtb16, y16, Bm, Cm, A + (size_t)layer*DQ*NQ, Dsk + (size_t)layer*DQ,
            ap, yact16);
        // y = yact @ Wlin + blin  (bf16 out, overwrites y16)
        gemm_db<false><<<gOut, blk, 0, stream>>>(
            yact16, Wt_lin + (size_t)layer*KQ*KQ, blin + (size_t)layer*DQ,
            (float*)nullptr, y16, DQ);
    }
    // decoder (fp32 out)
    gemm_db<true><<<gOut, blk, 0, stream>>>(
        y16, Wt_dec, bdec, out, (unsigned short*)nullptr, DQ);
}